// Round 7
// baseline (451.031 us; speedup 1.0000x reference)
//
#include <hip/hip_runtime.h>

#define D 64
#define SH 10             // bucket = key >> SH; 1024 keys/bucket
#define BK 1024
#define NBLK 256          // blocks for sort passes A1/A2
#define PGRID 768         // persistent-GEMM grid cap (3 blocks/CU)

typedef _Float16 half4v __attribute__((ext_vector_type(4)));
typedef _Float16 half8 __attribute__((ext_vector_type(8)));
typedef float f32x4 __attribute__((ext_vector_type(4)));

__device__ __forceinline__ float fast_tanh(float x) {
    float e = __expf(2.f * x);
    return 1.f - 2.f * __builtin_amdgcn_rcpf(e + 1.f);
}

// Split two f32x4 (8 consecutive k) into fp16 hi + fp16 residual half8s.
__device__ __forceinline__ void split8v(const f32x4& x, const f32x4& y,
                                        half8& h, half8& r) {
#pragma unroll
    for (int j = 0; j < 4; ++j) {
        _Float16 a = (_Float16)x[j];
        h[j] = a; r[j] = (_Float16)(x[j] - (float)a);
        _Float16 b = (_Float16)y[j];
        h[j + 4] = b; r[j + 4] = (_Float16)(y[j] - (float)b);
    }
}

// In-register 4x4 transpose across lanes u = lane&3 (regs r).
__device__ __forceinline__ void transpose4(f32x4& x, int u) {
    const bool b = (u & 1) != 0;
    float t0 = b ? x[0] : x[1];
    float t1 = b ? x[2] : x[3];
    t0 = __shfl_xor(t0, 1);
    t1 = __shfl_xor(t1, 1);
    x[0] = b ? t0 : x[0];
    x[1] = b ? x[1] : t0;
    x[2] = b ? t1 : x[2];
    x[3] = b ? x[3] : t1;
    const bool c = (u & 2) != 0;
    float s0 = c ? x[0] : x[2];
    float s1 = c ? x[1] : x[3];
    s0 = __shfl_xor(s0, 2);
    s1 = __shfl_xor(s1, 2);
    x[0] = c ? s0 : x[0];
    x[1] = c ? s1 : x[1];
    x[2] = c ? x[2] : s0;
    x[3] = c ? x[3] : s1;
}

// Gather one dst row's sum of fp16 src rows (csr segment), 16-lane group,
// 4-deep unroll — EXACT same summation order as the old standalone gather.
__device__ __forceinline__ f32x4 gather_row(const _Float16* __restrict__ src,
                                            const int* __restrict__ csr,
                                            int st, int en, int sub) {
    f32x4 a0 = {}, a1 = {}, a2 = {}, a3 = {};
    int j = st;
    for (; j + 3 < en; j += 4) {
        int c0 = csr[j], c1 = csr[j + 1], c2 = csr[j + 2], c3 = csr[j + 3];
        half4v v0 = *(const half4v*)&src[((size_t)c0 << 6) + sub * 4];
        half4v v1 = *(const half4v*)&src[((size_t)c1 << 6) + sub * 4];
        half4v v2 = *(const half4v*)&src[((size_t)c2 << 6) + sub * 4];
        half4v v3 = *(const half4v*)&src[((size_t)c3 << 6) + sub * 4];
        a0 += __builtin_convertvector(v0, f32x4);
        a1 += __builtin_convertvector(v1, f32x4);
        a2 += __builtin_convertvector(v2, f32x4);
        a3 += __builtin_convertvector(v3, f32x4);
    }
    for (; j < en; ++j) {
        int c = csr[j];
        half4v v = *(const half4v*)&src[((size_t)c << 6) + sub * 4];
        a0 += __builtin_convertvector(v, f32x4);
    }
    return (a0 + a1) + (a2 + a3);
}

// ---------------------------------------------------------------------------
// Plain persistent split-fp16 MFMA GEMM (used for hproj): C = A @ W, fp16 out.
// Round-6 structure: W in regs, coalesced A stage via swizzled LDS, linear out.
// ---------------------------------------------------------------------------
template <int WF, int WH>
__global__ __launch_bounds__(256, 3) void gemm64(const float* __restrict__ A,
                                                 const float* __restrict__ W,
                                                 float* __restrict__ Cf,
                                                 _Float16* __restrict__ Ch,
                                                 int M, int ntiles) {
    __shared__ float Ab[4096];
    __shared__ float Ob[4096];
    const int tid = threadIdx.x;
    const int lane = tid & 63;
    const int rt = tid >> 6;
    const int m = lane & 15;
    const int q = lane >> 4;
    const int u = m & 3, g = m >> 2;

    half8 bh[2][4], br[2][4];
#pragma unroll
    for (int kc2 = 0; kc2 < 2; ++kc2)
#pragma unroll
        for (int ct = 0; ct < 4; ++ct)
#pragma unroll
            for (int j = 0; j < 8; ++j) {
                float w = W[(kc2 * 32 + q * 8 + j) * D + ct * 16 + m];
                _Float16 h = (_Float16)w;
                bh[kc2][ct][j] = h;
                br[kc2][ct][j] = (_Float16)(w - (float)h);
            }

    const int lr = rt * 16 + m;
    const int ls = (lr & 7) << 2;
    const int fa0 = lr * 64 + ((q * 8)      ^ ls);
    const int fa1 = lr * 64 + ((q * 8 + 4)  ^ ls);
    const int fa2 = lr * 64 + ((q * 8 + 32) ^ ls);
    const int fa3 = lr * 64 + ((q * 8 + 36) ^ ls);
    const int er = rt * 16 + q * 4 + u;
    const int es = (er & 7) << 2;
    (void)es;

    for (int tile = blockIdx.x; tile < ntiles; tile += gridDim.x) {
        const int base = tile * 64;
        // coalesced stage (guarded per-row for the tail tile)
        const float* At = A + (size_t)base * D;
        f32x4 av[4];
#pragma unroll
        for (int i = 0; i < 4; ++i) {
            int gf = i * 1024 + tid * 4;
            av[i] = (base + (gf >> 6) < M) ? *(const f32x4*)(At + gf) : f32x4{};
        }
#pragma unroll
        for (int i = 0; i < 4; ++i) {
            int gf = i * 1024 + tid * 4;
            int row = gf >> 6, cf = gf & 63;
            *(f32x4*)&Ab[row * 64 + (cf ^ ((row & 7) << 2))] = av[i];
        }
        __syncthreads();

        f32x4 a0 = *(const f32x4*)&Ab[fa0];
        f32x4 a1 = *(const f32x4*)&Ab[fa1];
        f32x4 a2 = *(const f32x4*)&Ab[fa2];
        f32x4 a3 = *(const f32x4*)&Ab[fa3];
        half8 ah0, ar0, ah1, ar1;
        split8v(a0, a1, ah0, ar0);
        split8v(a2, a3, ah1, ar1);

        f32x4 acc[4] = {};
#pragma unroll
        for (int ct = 0; ct < 4; ++ct) {
            acc[ct] = __builtin_amdgcn_mfma_f32_16x16x32_f16(ah0, bh[0][ct], acc[ct], 0, 0, 0);
            acc[ct] = __builtin_amdgcn_mfma_f32_16x16x32_f16(ar0, bh[0][ct], acc[ct], 0, 0, 0);
            acc[ct] = __builtin_amdgcn_mfma_f32_16x16x32_f16(ah0, br[0][ct], acc[ct], 0, 0, 0);
            acc[ct] = __builtin_amdgcn_mfma_f32_16x16x32_f16(ah1, bh[1][ct], acc[ct], 0, 0, 0);
            acc[ct] = __builtin_amdgcn_mfma_f32_16x16x32_f16(ar1, bh[1][ct], acc[ct], 0, 0, 0);
            acc[ct] = __builtin_amdgcn_mfma_f32_16x16x32_f16(ah1, br[1][ct], acc[ct], 0, 0, 0);
        }
#pragma unroll
        for (int ct = 0; ct < 4; ++ct) transpose4(acc[ct], u);
#pragma unroll
        for (int ct = 0; ct < 4; ++ct)
            *(f32x4*)&Ob[er * 64 + ((ct * 16 + g * 4) ^ es)] = acc[ct];
        __syncthreads();

#pragma unroll
        for (int j = 0; j < 4; ++j) {
            int gf = j * 1024 + tid * 4;
            int row = gf >> 6, cf = gf & 63;
            if (base + row < M) {
                f32x4 v = *(const f32x4*)&Ob[row * 64 + (cf ^ ((row & 7) << 2))];
                if (WF) *(f32x4*)&Cf[(size_t)base * D + gf] = v;
                if (WH) {
                    half4v hv;
                    hv.x = (_Float16)v[0]; hv.y = (_Float16)v[1];
                    hv.z = (_Float16)v[2]; hv.w = (_Float16)v[3];
                    *(half4v*)&Ch[(size_t)base * D + gf] = hv;
                }
            }
        }
    }
}

// ---------------------------------------------------------------------------
// Phase-1 fused: per tile, GATHER the tile's gate rows (hproj fp16, L3-hot)
// into LDS, then C = tanh((A@W) * gate); writes f32 + fp16. Eliminates the
// 51.2MB nbuf round-trip and the standalone gather dispatch.
// ---------------------------------------------------------------------------
__global__ __launch_bounds__(256, 3) void gemm64_gath(
        const float* __restrict__ A, const float* __restrict__ W,
        const _Float16* __restrict__ hsrc,
        const int* __restrict__ csr, const int* __restrict__ offs,
        const int* __restrict__ counts,
        float* __restrict__ Cf, _Float16* __restrict__ Ch,
        int M, int ntiles) {
    __shared__ float Ab[4096];
    __shared__ float Gb[4096];
    __shared__ float Ob[4096];
    const int tid = threadIdx.x;
    const int lane = tid & 63;
    const int rt = tid >> 6;
    const int m = lane & 15;
    const int q = lane >> 4;
    const int u = m & 3, g = m >> 2;
    const int gi = tid >> 4, sub = tid & 15;   // gather group / lane

    half8 bh[2][4], br[2][4];
#pragma unroll
    for (int kc2 = 0; kc2 < 2; ++kc2)
#pragma unroll
        for (int ct = 0; ct < 4; ++ct)
#pragma unroll
            for (int j = 0; j < 8; ++j) {
                float w = W[(kc2 * 32 + q * 8 + j) * D + ct * 16 + m];
                _Float16 h = (_Float16)w;
                bh[kc2][ct][j] = h;
                br[kc2][ct][j] = (_Float16)(w - (float)h);
            }

    const int lr = rt * 16 + m;
    const int ls = (lr & 7) << 2;
    const int fa0 = lr * 64 + ((q * 8)      ^ ls);
    const int fa1 = lr * 64 + ((q * 8 + 4)  ^ ls);
    const int fa2 = lr * 64 + ((q * 8 + 32) ^ ls);
    const int fa3 = lr * 64 + ((q * 8 + 36) ^ ls);
    const int er = rt * 16 + q * 4 + u;
    const int es = (er & 7) << 2;

    for (int tile = blockIdx.x; tile < ntiles; tile += gridDim.x) {
        const int base = tile * 64;

        // ---- issue A loads first (HBM latency hides under the gather) ----
        const float* At = A + (size_t)base * D;
        f32x4 av[4];
#pragma unroll
        for (int i = 0; i < 4; ++i) {
            int gf = i * 1024 + tid * 4;
            av[i] = (base + (gf >> 6) < M) ? *(const f32x4*)(At + gf) : f32x4{};
        }

        // ---- in-block gather: 16-lane group per row, 4 rows/group ----
#pragma unroll
        for (int r4 = 0; r4 < 4; ++r4) {
            const int lrow = gi * 4 + r4;
            const int row = base + lrow;
            f32x4 rsum = {};
            if (row < M) {
                const int st = offs[row];
                rsum = gather_row(hsrc, csr, st, st + counts[row], sub);
            }
            *(f32x4*)&Gb[lrow * 64 + ((sub * 4) ^ ((lrow & 7) << 2))] = rsum;
        }

        // ---- stage A into swizzled LDS ----
#pragma unroll
        for (int i = 0; i < 4; ++i) {
            int gf = i * 1024 + tid * 4;
            int row = gf >> 6, cf = gf & 63;
            *(f32x4*)&Ab[row * 64 + (cf ^ ((row & 7) << 2))] = av[i];
        }
        __syncthreads();

        f32x4 a0 = *(const f32x4*)&Ab[fa0];
        f32x4 a1 = *(const f32x4*)&Ab[fa1];
        f32x4 a2 = *(const f32x4*)&Ab[fa2];
        f32x4 a3 = *(const f32x4*)&Ab[fa3];
        half8 ah0, ar0, ah1, ar1;
        split8v(a0, a1, ah0, ar0);
        split8v(a2, a3, ah1, ar1);

        f32x4 acc[4] = {};
#pragma unroll
        for (int ct = 0; ct < 4; ++ct) {
            acc[ct] = __builtin_amdgcn_mfma_f32_16x16x32_f16(ah0, bh[0][ct], acc[ct], 0, 0, 0);
            acc[ct] = __builtin_amdgcn_mfma_f32_16x16x32_f16(ar0, bh[0][ct], acc[ct], 0, 0, 0);
            acc[ct] = __builtin_amdgcn_mfma_f32_16x16x32_f16(ah0, br[0][ct], acc[ct], 0, 0, 0);
            acc[ct] = __builtin_amdgcn_mfma_f32_16x16x32_f16(ah1, bh[1][ct], acc[ct], 0, 0, 0);
            acc[ct] = __builtin_amdgcn_mfma_f32_16x16x32_f16(ar1, bh[1][ct], acc[ct], 0, 0, 0);
            acc[ct] = __builtin_amdgcn_mfma_f32_16x16x32_f16(ah1, br[1][ct], acc[ct], 0, 0, 0);
        }
#pragma unroll
        for (int ct = 0; ct < 4; ++ct) transpose4(acc[ct], u);

#pragma unroll
        for (int ct = 0; ct < 4; ++ct) {
            f32x4 v = acc[ct];
            f32x4 gv = *(const f32x4*)&Gb[er * 64 + ((ct * 16 + g * 4) ^ es)];
            v[0] = fast_tanh(v[0] * gv[0]);
            v[1] = fast_tanh(v[1] * gv[1]);
            v[2] = fast_tanh(v[2] * gv[2]);
            v[3] = fast_tanh(v[3] * gv[3]);
            *(f32x4*)&Ob[er * 64 + ((ct * 16 + g * 4) ^ es)] = v;
        }
        __syncthreads();

#pragma unroll
        for (int j = 0; j < 4; ++j) {
            int gf = j * 1024 + tid * 4;
            int row = gf >> 6, cf = gf & 63;
            if (base + row < M) {
                f32x4 v = *(const f32x4*)&Ob[row * 64 + (cf ^ ((row & 7) << 2))];
                *(f32x4*)&Cf[(size_t)base * D + gf] = v;
                half4v hv;
                hv.x = (_Float16)v[0]; hv.y = (_Float16)v[1];
                hv.z = (_Float16)v[2]; hv.w = (_Float16)v[3];
                *(half4v*)&Ch[(size_t)base * D + gf] = hv;
            }
        }
    }
}

// Stage one 64x64 W into LDS transposed fp16 hi+re, XOR-swizzled.
__device__ __forceinline__ void stage_w(const float* __restrict__ W, char* lb,
                                        int n, int kg, int b0, int b1) {
    float wf[16];
#pragma unroll
    for (int j = 0; j < 16; ++j) wf[j] = W[(kg * 16 + j) * D + n];
    half8 h0, h1, r0, r1;
#pragma unroll
    for (int j = 0; j < 8; ++j) {
        _Float16 a = (_Float16)wf[j];
        h0[j] = a; r0[j] = (_Float16)(wf[j] - (float)a);
        _Float16 b = (_Float16)wf[j + 8];
        h1[j] = b; r1[j] = (_Float16)(wf[j + 8] - (float)b);
    }
    *(half8*)(lb + b0) = h0;
    *(half8*)(lb + b1) = h1;
    *(half8*)(lb + 8192 + b0) = r0;
    *(half8*)(lb + 8192 + b1) = r1;
}

// ---------------------------------------------------------------------------
// Phase-2 fused+gather: Cf = tanh(((gather nodeh)@W1) * (A2@W2)).
// Gathers agg rows straight into the Ab LDS that feeds the MFMA A1 operand —
// no 25.6MB agg round-trip, no standalone gather dispatch. Persistent; W1/W2
// staged once (32KB); 2 barriers/tile.
// ---------------------------------------------------------------------------
__global__ __launch_bounds__(256, 3) void gemm64_fused_gath(
        const _Float16* __restrict__ nsrc,
        const int* __restrict__ csr, const int* __restrict__ offs,
        const int* __restrict__ counts,
        const float* __restrict__ W1,
        const float* __restrict__ A2, const float* __restrict__ W2,
        float* __restrict__ Cf, int M, int ntiles) {
    __shared__ float Ab[4096];        // 16KB agg tile (swizzled f32)
    __shared__ _Float16 Wlds[16384];  // 32KB: W1hi,W1re,W2hi,W2re
    const int tid = threadIdx.x;
    const int lane = tid & 63;
    const int rt = tid >> 6;
    const int m = lane & 15;
    const int q = lane >> 4;
    const int u = m & 3, g = m >> 2;
    const int gi = tid >> 4, sub = tid & 15;

    char* lb = (char*)Wlds;
    {
        const int n = tid & 63, kg = tid >> 6;
        const int b0 = (n * 128 + kg * 32) ^ ((n & 7) << 4);
        const int b1 = (n * 128 + kg * 32 + 16) ^ ((n & 7) << 4);
        stage_w(W1, lb, n, kg, b0, b1);
        stage_w(W2, lb + 16384, n, kg, b0, b1);
    }
    // first in-loop barrier covers W staging

    const int lr = rt * 16 + m;
    const int ls = (lr & 7) << 2;
    const int fa0 = lr * 64 + ((q * 8)      ^ ls);
    const int fa1 = lr * 64 + ((q * 8 + 4)  ^ ls);
    const int fa2 = lr * 64 + ((q * 8 + 32) ^ ls);
    const int fa3 = lr * 64 + ((q * 8 + 36) ^ ls);

    for (int tile = blockIdx.x; tile < ntiles; tile += gridDim.x) {
        const int base = tile * 64;

        // issue A2 (hedge) strided loads early
        const int arow = base + rt * 16 + m;
        const size_t aoff = (size_t)(arow < M ? arow : 0) * D + q * 8;
        f32x4 s0 = *(const f32x4*)(A2 + aoff);
        f32x4 s1 = *(const f32x4*)(A2 + aoff + 4);
        f32x4 s2 = *(const f32x4*)(A2 + aoff + 32);
        f32x4 s3 = *(const f32x4*)(A2 + aoff + 36);

        // gather agg rows into Ab (L3-hot nodeh reads overlap A2 loads)
#pragma unroll
        for (int r4 = 0; r4 < 4; ++r4) {
            const int lrow = gi * 4 + r4;
            const int row = base + lrow;
            f32x4 rsum = {};
            if (row < M) {
                const int st = offs[row];
                rsum = gather_row(nsrc, csr, st, st + counts[row], sub);
            }
            *(f32x4*)&Ab[lrow * 64 + ((sub * 4) ^ ((lrow & 7) << 2))] = rsum;
        }
        __syncthreads();

        f32x4 p0 = *(const f32x4*)&Ab[fa0];
        f32x4 p1 = *(const f32x4*)&Ab[fa1];
        f32x4 p2 = *(const f32x4*)&Ab[fa2];
        f32x4 p3 = *(const f32x4*)&Ab[fa3];
        __syncthreads();   // Ab reads done; next tile may overwrite

        half8 pah0, par0, pah1, par1, sah0, sar0, sah1, sar1;
        split8v(p0, p1, pah0, par0);
        split8v(p2, p3, pah1, par1);
        split8v(s0, s1, sah0, sar0);
        split8v(s2, s3, sah1, sar1);

        f32x4 acc1[4] = {}, acc2[4] = {};
#pragma unroll
        for (int kc2 = 0; kc2 < 2; ++kc2) {
            half8 pah = kc2 ? pah1 : pah0;
            half8 par = kc2 ? par1 : par0;
            half8 sah = kc2 ? sah1 : sah0;
            half8 sar = kc2 ? sar1 : sar0;
#pragma unroll
            for (int ct = 0; ct < 4; ++ct) {
                int n2 = ct * 16 + m;
                int boff = (n2 * 128 + kc2 * 64 + q * 16) ^ ((n2 & 7) << 4);
                half8 wh = *(const half8*)(lb + boff);
                half8 wr = *(const half8*)(lb + 8192 + boff);
                acc1[ct] = __builtin_amdgcn_mfma_f32_16x16x32_f16(pah, wh, acc1[ct], 0, 0, 0);
                acc1[ct] = __builtin_amdgcn_mfma_f32_16x16x32_f16(par, wh, acc1[ct], 0, 0, 0);
                acc1[ct] = __builtin_amdgcn_mfma_f32_16x16x32_f16(pah, wr, acc1[ct], 0, 0, 0);
                half8 ch = *(const half8*)(lb + 16384 + boff);
                half8 cr = *(const half8*)(lb + 24576 + boff);
                acc2[ct] = __builtin_amdgcn_mfma_f32_16x16x32_f16(sah, ch, acc2[ct], 0, 0, 0);
                acc2[ct] = __builtin_amdgcn_mfma_f32_16x16x32_f16(sar, ch, acc2[ct], 0, 0, 0);
                acc2[ct] = __builtin_amdgcn_mfma_f32_16x16x32_f16(sah, cr, acc2[ct], 0, 0, 0);
            }
        }

#pragma unroll
        for (int ct = 0; ct < 4; ++ct) {
            transpose4(acc1[ct], u);
            transpose4(acc2[ct], u);
        }

        const int orow = base + rt * 16 + q * 4 + u;
        if (orow < M) {
            const size_t ro = (size_t)orow * D + g * 4;
#pragma unroll
            for (int ct = 0; ct < 4; ++ct) {
                f32x4 v;
                v[0] = fast_tanh(acc1[ct][0] * acc2[ct][0]);
                v[1] = fast_tanh(acc1[ct][1] * acc2[ct][1]);
                v[2] = fast_tanh(acc1[ct][2] * acc2[ct][2]);
                v[3] = fast_tanh(acc1[ct][3] * acc2[ct][3]);
                *(f32x4*)&Cf[ro + ct * 16] = v;
            }
        }
    }
}

// --------------------- zero-global-atomic counting sort ---------------------
__global__ __launch_bounds__(256) void sort_hist(const int* __restrict__ keys,
                                                 int* __restrict__ cmat,
                                                 int n, int B, int ipb) {
    __shared__ int h[256];
    const int tid = threadIdx.x;
    for (int i = tid; i < B; i += 256) h[i] = 0;
    __syncthreads();
    const int start = blockIdx.x * ipb;
    const int end = (start + ipb < n) ? start + ipb : n;
    for (int i = start + tid; i < end; i += 256)
        atomicAdd(&h[keys[i] >> SH], 1);
    __syncthreads();
    for (int b = tid; b < B; b += 256) cmat[b * NBLK + blockIdx.x] = h[b];
}

__global__ __launch_bounds__(256) void scan1(const int* __restrict__ src,
                                             int* __restrict__ dst,
                                             int* __restrict__ bsums, int n) {
    __shared__ int s[256];
    const int t = threadIdx.x;
    const int base = blockIdx.x * 1024 + t * 4;
    int v[4];
#pragma unroll
    for (int j = 0; j < 4; ++j) v[j] = (base + j < n) ? src[base + j] : 0;
    int tsum = v[0] + v[1] + v[2] + v[3];
    s[t] = tsum;
    __syncthreads();
    for (int o = 1; o < 256; o <<= 1) {
        int x = (t >= o) ? s[t - o] : 0;
        __syncthreads();
        s[t] += x;
        __syncthreads();
    }
    int run = s[t] - tsum;
    if (t == 255) bsums[blockIdx.x] = s[255];
#pragma unroll
    for (int j = 0; j < 4; ++j) {
        if (base + j < n) dst[base + j] = run;
        run += v[j];
    }
}

// Fused scan2+scan3.
__global__ __launch_bounds__(256) void scan23(int* __restrict__ a,
                                              const int* __restrict__ bsums,
                                              int n, int nb) {
    __shared__ int sb[256];
    const int t = threadIdx.x;
    int v = (t < nb) ? bsums[t] : 0;
    sb[t] = v;
    __syncthreads();
    for (int o = 1; o < 256; o <<= 1) {
        int x = (t >= o) ? sb[t - o] : 0;
        __syncthreads();
        sb[t] += x;
        __syncthreads();
    }
    int incl = sb[t];
    __syncthreads();
    sb[t] = incl - v;          // exclusive block prefix
    __syncthreads();
    int i = blockIdx.x * 256 + t;
    if (i < n) a[i] += sb[i >> 10];
}

__global__ __launch_bounds__(256) void sort_scatter(const int* __restrict__ keys,
                                                    const int* __restrict__ vals,
                                                    const int* __restrict__ cscan,
                                                    int* __restrict__ bucketed,
                                                    int n, int B, int ipb) {
    __shared__ int cur[256];
    const int tid = threadIdx.x;
    for (int i = tid; i < B; i += 256) cur[i] = cscan[i * NBLK + blockIdx.x];
    __syncthreads();
    const int start = blockIdx.x * ipb;
    const int end = (start + ipb < n) ? start + ipb : n;
    for (int i = start + tid; i < end; i += 256) {
        int k = keys[i];
        int p = atomicAdd(&cur[k >> SH], 1);
        bucketed[p] = (vals[i] << SH) | (k & (BK - 1));
    }
}

// Pass B: per-bucket exact CSR, 1024 keys/bucket
__global__ __launch_bounds__(256) void sort_finalize(const int* __restrict__ bucketed,
                                                     const int* __restrict__ cscan,
                                                     int* __restrict__ csr,
                                                     int* __restrict__ offs,
                                                     int* __restrict__ counts,
                                                     int n, int B, int nkeys) {
    __shared__ int h[BK];
    __shared__ int s[256];
    const int t = threadIdx.x;
    const int b = blockIdx.x;
    const int bstart = cscan[b * NBLK];
    const int bend = (b + 1 < B) ? cscan[(b + 1) * NBLK] : n;

    for (int i = t; i < BK; i += 256) h[i] = 0;
    __syncthreads();
    for (int i = bstart + t; i < bend; i += 256)
        atomicAdd(&h[bucketed[i] & (BK - 1)], 1);
    __syncthreads();
    const int c0 = h[t * 4], c1 = h[t * 4 + 1], c2 = h[t * 4 + 2], c3 = h[t * 4 + 3];
    const int tsum = c0 + c1 + c2 + c3;
    s[t] = tsum;
    __syncthreads();
    for (int o = 1; o < 256; o <<= 1) {
        int x = (t >= o) ? s[t - o] : 0;
        __syncthreads();
        s[t] += x;
        __syncthreads();
    }
    const int e0 = s[t] - tsum;
    const int e1 = e0 + c0, e2 = e1 + c1, e3 = e2 + c2;
    const int keyb = b * BK + t * 4;
    if (keyb + 0 < nkeys) { offs[keyb + 0] = bstart + e0; counts[keyb + 0] = c0; }
    if (keyb + 1 < nkeys) { offs[keyb + 1] = bstart + e1; counts[keyb + 1] = c1; }
    if (keyb + 2 < nkeys) { offs[keyb + 2] = bstart + e2; counts[keyb + 2] = c2; }
    if (keyb + 3 < nkeys) { offs[keyb + 3] = bstart + e3; counts[keyb + 3] = c3; }
    h[t * 4 + 0] = bstart + e0;
    h[t * 4 + 1] = bstart + e1;
    h[t * 4 + 2] = bstart + e2;
    h[t * 4 + 3] = bstart + e3;
    __syncthreads();
    for (int i = bstart + t; i < bend; i += 256) {
        int e = bucketed[i];
        int p = atomicAdd(&h[e & (BK - 1)], 1);
        csr[p] = e >> SH;
    }
}

static void build_csr(const int* keys, const int* vals, int NI, int nkeys,
                      int* cmat, int* cscan, int* bsums, int* bucketed,
                      int* csr, int* offs, int* counts, hipStream_t stream) {
    const int B = (nkeys + BK - 1) >> SH;
    const int L = B * NBLK;
    const int ipb = (NI + NBLK - 1) / NBLK;
    const int nsb = (L + 1023) / 1024;
    sort_hist<<<NBLK, 256, 0, stream>>>(keys, cmat, NI, B, ipb);
    scan1<<<nsb, 256, 0, stream>>>(cmat, cscan, bsums, L);
    scan23<<<(L + 255) / 256, 256, 0, stream>>>(cscan, bsums, L, nsb);
    sort_scatter<<<NBLK, 256, 0, stream>>>(keys, vals, cscan, bucketed, NI, B, ipb);
    sort_finalize<<<B, 256, 0, stream>>>(bucketed, cscan, csr, offs, counts, NI, B, nkeys);
}

extern "C" void kernel_launch(void* const* d_in, const int* in_sizes, int n_in,
                              void* d_out, int out_size, void* d_ws, size_t ws_size,
                              hipStream_t stream) {
    const float* node  = (const float*)d_in[0];
    const float* hedge = (const float*)d_in[1];
    const float* W_nn  = (const float*)d_in[2];
    const float* W_nh  = (const float*)d_in[3];
    const float* W_hh  = (const float*)d_in[4];
    const float* W_hn  = (const float*)d_in[5];
    const int* node_idx  = (const int*)d_in[6];
    const int* hedge_idx = (const int*)d_in[7];

    const int N  = in_sizes[0] / D;   // 200,000
    const int E  = in_sizes[1] / D;   // 100,000
    const int NI = in_sizes[6];       // 1,600,000
    const int maxNE = (N > E) ? N : E;
    const int maxB = (maxNE + BK - 1) >> SH;

    float* out_node  = (float*)d_out;                  // [N,64]
    float* out_hedge = out_node + (size_t)N * D;       // [E,64] (scratch: hproj fp16)

    float*     nbuf     = (float*)d_ws;                // (kept for layout; unused)
    int*       bucketed = (int*)(nbuf + (size_t)N * D);
    int*       csr      = bucketed + NI;
    int*       cmat     = csr + NI;
    int*       cscan    = cmat + (size_t)maxB * NBLK;
    int*       offs     = cscan + (size_t)maxB * NBLK;
    int*       counts   = offs + maxNE;
    int*       bsums    = counts + maxNE;
    _Float16*  nodeh    = (_Float16*)(bsums + 256);

    const int gbE = (E + 63) / 64;
    const int gbN = (N + 63) / 64;
    const int GE = gbE < PGRID ? gbE : PGRID;
    const int GN = gbN < PGRID ? gbN : PGRID;

    // ---------- phase 1 ----------
    build_csr(node_idx, hedge_idx, NI, N, cmat, cscan, bsums, bucketed,
              csr, offs, counts, stream);
    // hproj = hedge @ W_nh (fp16 into out_hedge scratch)
    gemm64<0, 1><<<GE, 256, 0, stream>>>(hedge, W_nh, nullptr,
                                         (_Float16*)out_hedge, E, gbE);
    // new_node = tanh((node@W_nn) * gather(hproj)); writes f32 + fp16
    gemm64_gath<<<GN, 256, 0, stream>>>(node, W_nn, (const _Float16*)out_hedge,
                                        csr, offs, counts, out_node, nodeh, N, gbN);

    // ---------- phase 2 ----------
    build_csr(hedge_idx, node_idx, NI, E, cmat, cscan, bsums, bucketed,
              csr, offs, counts, stream);
    // new_hedge = tanh(((gather nodeh)@W_hn) * (hedge@W_hh))
    gemm64_fused_gath<<<GE, 256, 0, stream>>>(nodeh, csr, offs, counts,
                                              W_hn, hedge, W_hh, out_hedge, E, gbE);
}